// Round 1
// baseline (77.745 us; speedup 1.0000x reference)
//
#include <hip/hip_runtime.h>
#include <math.h>

#define KK 49
#define H 128
#define W 128
#define C 64
#define NB 4
#define PLANE (H * W)

// ---- packed, pre-normalized f16 halo layout in workspace ----
// xh[b][g][hp][wp] : uint4 slot = 8 f16 channels (group g = ch 8g..8g+7),
// hp = gh+3, wp = gw+3, apron (3 px) and tail rows/cols are EXACT ZEROS.
#define HP 136
#define WP 136
#define PSLOT (HP * WP)          // 18496 slots per (b,g) plane
// total: 4*8*18496 slots * 16 B = 9.47 MB  (ws is ~256 MB)

#define RW 32                    // sim block region width (px)
#define RH 4                     // sim block region height (px)
#define TSTR 132                 // transpose buffer stride (128 px + 4 stagger)

// R15 = two-kernel split of the verified R13/R14 Gram-MFMA formulation.
//  K1 (pack): one pass over x, per-pixel rnorm, writes PRE-NORMALIZED f16
//     8ch-packed padded planes. Normalizing before packing makes the Gram
//     dot product the cosine similarity directly -> no norm array, no norm
//     phase, no per-element divides in K2. Boundary zeros reproduce the
//     reference's 0/(0+eps)=0 entries exactly.
//  K2 (sim): same wave geometry / MFMA lane mapping / masks / transpose /
//     store as the verified kernel, but A/B fragments load straight from
//     the packed global array (L2/L3-resident, XCD-banded swizzle kept).
//     No LDS staging, no staging barriers; LDS = 26 KB transpose buf only.

typedef _Float16 h2_t __attribute__((ext_vector_type(2)));
typedef _Float16 v8h  __attribute__((ext_vector_type(8)));
typedef float    v4f  __attribute__((ext_vector_type(4)));

__device__ __forceinline__ unsigned int packh2(float a, float b) {
    return __builtin_bit_cast(unsigned int, __builtin_amdgcn_cvt_pkrtz(a, b));
}

// ---------------- K1: pack + normalize ----------------
// 256 blocks x 256 threads; each block owns 289 consecutive (b,hp,wp)
// positions (256*289 = 73984 = 4*136*136) -> perfectly balanced, coalesced.
__global__ __launch_bounds__(256, 4) void pack_kernel(const float* __restrict__ x,
                                                      uint4* __restrict__ xh) {
    const int base = blockIdx.x * 289;
#pragma unroll
    for (int it = 0; it < 2; ++it) {
        int n;
        if (it == 0) {
            n = base + threadIdx.x;
        } else {
            if (threadIdx.x >= 33) break;   // 289 - 256 = 33 extras
            n = base + 256 + threadIdx.x;
        }
        const int b   = n / PSLOT;
        const int rem = n - b * PSLOT;
        const int hp  = rem / WP;
        const int wp  = rem - hp * WP;
        const int gh  = hp - 3;
        const int gw  = wp - 3;
        uint4* dst = xh + (size_t)b * 8 * PSLOT + hp * WP + wp;
        if ((unsigned)gh < (unsigned)H && (unsigned)gw < (unsigned)W) {
            const float* p = x + (size_t)b * C * PLANE + gh * W + gw;
            float v[C];
#pragma unroll
            for (int c = 0; c < C; ++c) v[c] = p[(size_t)c * PLANE];
            float ss = 0.f;
#pragma unroll
            for (int c = 0; c < C; ++c) ss = fmaf(v[c], v[c], ss);
            const float rn = (ss > 0.f) ? rsqrtf(ss) : 0.f;
#pragma unroll
            for (int g = 0; g < 8; ++g) {
                uint4 u;
                u.x = packh2(v[8 * g + 0] * rn, v[8 * g + 1] * rn);
                u.y = packh2(v[8 * g + 2] * rn, v[8 * g + 3] * rn);
                u.z = packh2(v[8 * g + 4] * rn, v[8 * g + 5] * rn);
                u.w = packh2(v[8 * g + 6] * rn, v[8 * g + 7] * rn);
                dst[(size_t)g * PSLOT] = u;
            }
        } else {
            const uint4 z = make_uint4(0u, 0u, 0u, 0u);
#pragma unroll
            for (int g = 0; g < 8; ++g) dst[(size_t)g * PSLOT] = z;
        }
    }
}

// ---------------- K2: Gram-MFMA similarity + softmax ----------------
__global__ __launch_bounds__(512, 4) void sim_kernel(const uint4* __restrict__ xh,
                                                     float* __restrict__ out) {
    __shared__ float trans[KK * TSTR];   // 25.9 KB

    const int tid = threadIdx.x;

    // XCD-banded swizzle (proven): each XCD owns 4 contiguous tile-rows/batch
    const int id  = blockIdx.x;
    const int xcd = id & 7;
    const int seq = id >> 3;          // 0..63
    const int b   = seq >> 4;         // 0..3
    const int rem = seq & 15;
    const int by  = xcd * 4 + (rem >> 2);  // 0..31
    const int bx  = rem & 3;               // 0..3
    const int h0  = by * RH;
    const int w0  = bx * RW;

    const int lane = tid & 63;
    const int tc   = tid >> 6;        // 0..7 (wave = A-tile col group)
    const int quad = lane >> 4;       // ch-chunk for frags; px-row for C
    const int l15  = lane & 15;
    const int sr   = l15 >> 2;
    const int sc   = l15 & 3;

    // global fragment addresses (slot units), identical geometry to the
    // verified LDS version: A at (h0+sr, w0+tc*4+sc); B(dr,dc) offset by
    // (dr*4-3, dc*4-3). In padded coords:
    const int aoff  = (h0 + 3 + sr) * WP + (w0 + tc * 4 + sc + 3);
    const int boff0 = (h0 + sr) * WP + (w0 + tc * 4 + sc);
    const uint4* __restrict__ bp = xh + (size_t)b * 8 * PSLOT;

    v4f acc[9];
#pragma unroll
    for (int f = 0; f < 9; ++f) acc[f] = (v4f)0.f;

#pragma unroll
    for (int t = 0; t < 2; ++t) {
        const int grp = 4 * t + quad;
        const uint4* __restrict__ gb = bp + (size_t)grp * PSLOT;
        const v8h a = __builtin_bit_cast(v8h, gb[aoff]);
#pragma unroll
        for (int dr = 0; dr < 3; ++dr) {
#pragma unroll
            for (int dc = 0; dc < 3; ++dc) {
                const v8h bb = __builtin_bit_cast(v8h, gb[boff0 + dr * 4 * WP + dc * 4]);
                acc[dr * 3 + dc] =
                    __builtin_amdgcn_mfma_f32_16x16x32_f16(a, bb, acc[dr * 3 + dc], 0, 0, 0);
            }
        }
    }

    // ---- epilogue: acc IS cosine similarity (inputs pre-normalized).
    // C-layout: col n = l15 (B px), row m = quad*4 + r (A px).
    float mx[4] = {-1e30f, -1e30f, -1e30f, -1e30f};
#pragma unroll
    for (int f = 0; f < 9; ++f) {
        const int dr = f / 3, dc = f % 3;
        const int d0 = dr * 4 + sr - quad;       // window-row idx if in [0,6]
#pragma unroll
        for (int r = 0; r < 4; ++r) {
            const int de = dc * 4 + sc - r;      // window-col idx if in [0,6]
            const bool val = ((unsigned)d0 <= 6u) && ((unsigned)de <= 6u);
            if (val) mx[r] = fmaxf(mx[r], acc[f][r]);
        }
    }
#pragma unroll
    for (int wd = 1; wd < 16; wd <<= 1)
#pragma unroll
        for (int r = 0; r < 4; ++r)
            mx[r] = fmaxf(mx[r], __shfl_xor(mx[r], wd, 64));

    float sm[4] = {0.f, 0.f, 0.f, 0.f};
#pragma unroll
    for (int f = 0; f < 9; ++f) {
        const int dr = f / 3, dc = f % 3;
        const int d0 = dr * 4 + sr - quad;
#pragma unroll
        for (int r = 0; r < 4; ++r) {
            const int de = dc * 4 + sc - r;
            const bool val = ((unsigned)d0 <= 6u) && ((unsigned)de <= 6u);
            const float e = val ? __expf(acc[f][r] - mx[r]) : 0.f;
            acc[f][r] = e;
            sm[r] += e;
        }
    }
#pragma unroll
    for (int wd = 1; wd < 16; wd <<= 1)
#pragma unroll
        for (int r = 0; r < 4; ++r)
            sm[r] += __shfl_xor(sm[r], wd, 64);

    // ---- transpose through LDS for full-line global stores
#pragma unroll
    for (int r = 0; r < 4; ++r) {
        const float inv = __fdividef(1.f, sm[r]);
        const int px = quad * 32 + tc * 4 + r;   // local px (row*32+col)
#pragma unroll
        for (int f = 0; f < 9; ++f) {
            const int dr = f / 3, dc = f % 3;
            const int d0 = dr * 4 + sr - quad;
            const int de = dc * 4 + sc - r;
            if (((unsigned)d0 <= 6u) && ((unsigned)de <= 6u)) {
                const int k = d0 * 7 + de;
                trans[k * TSTR + px] = acc[f][r] * inv;
            }
        }
    }
    __syncthreads();

    const size_t obase = ((size_t)b * KK) << 14;
#pragma unroll
    for (int j = 0; j < 13; ++j) {
        const int n = tid + j * 512;             // n = k*128 + px, n < 6272
        if (n < KK * 128) {
            const int k  = n >> 7;
            const int px = n & 127;
            const int gh = h0 + (px >> 5);
            const int gw = w0 + (px & 31);
            out[obase + ((size_t)k << 14) + (gh << 7) + gw] = trans[k * TSTR + px];
        }
    }
}

extern "C" void kernel_launch(void* const* d_in, const int* in_sizes, int n_in,
                              void* d_out, int out_size, void* d_ws, size_t ws_size,
                              hipStream_t stream) {
    const float* x = (const float*)d_in[0];
    float* out = (float*)d_out;
    uint4* xh = (uint4*)d_ws;    // 9.47 MB of the ~256 MB workspace

    pack_kernel<<<dim3(256), dim3(256), 0, stream>>>(x, xh);
    sim_kernel<<<dim3(512), dim3(512), 0, stream>>>(xh, out);
}

// Round 2
// 75.253 us; speedup vs baseline: 1.0331x; 1.0331x over previous
//
#include <hip/hip_runtime.h>
#include <math.h>

#define KK 49
#define H 128
#define W 128
#define C 64
#define NB 4
#define EPS 1e-7f
#define PLANE (H * W)

#define RW 32               // block region width (px)
#define RH 4                // block region height (px)
#define HWP 40              // halo array width : 38 used + 2 pad (B-tile reach)
#define HHP 12              // halo array height: 10 used + 2 pad
#define NPOS (HWP * HHP)    // 480 slots
#define TSTR 132            // transpose buffer stride (128 px + 4 bank-stagger)

// R16 = revert to R14 (best measured: 74.0 us). R15's two-kernel split
// removed most kernel-side work yet cost +3.7 us => dur_us is dominated by
// harness re-poison fill (43.5 us @ 77% HBM peak) + per-dispatch overhead;
// node count is the lever, so single-dispatch is optimal.
// R14: Gram-MFMA formulation, XCD swizzle, f16 staging with WIDE loads:
// since w0 is 32-aligned, every 4-px float4 halo chunk is either fully
// in-image or fully out -> pure dwordx4 path, no edge scalars.
// Item = (ch-group g, halo row hr, chunk mi): 8 independent dwordx4 loads,
// 16 cvt_pkrtz, 4 ds_write_b128; 800 items/block, <=2/thread. Norms are a
// post-barrier LDS read-back (60 wave-b128). Unwritten slots are only pad
// rows 10-11 + (row9,col39), consumed exclusively by mask-discarded C
// entries -> garbage-safe, no zero-fill.
// MFMA: per wave A-tile = 16 px (4x4), 9 neighbor B-tiles, C = A.B^T via
// mfma_f32_16x16x32_f16, operands loaded identically from the 8-ch-packed
// uint4 slots (same-layout => Gram; R13-verified, absmax 2.4e-4).
// LAUNCH BOUNDS rule (R4/R5): 2nd arg caps VGPR at 256/arg -> (512,2) = 128.

typedef _Float16 h2_t __attribute__((ext_vector_type(2)));
typedef _Float16 v8h  __attribute__((ext_vector_type(8)));
typedef float    v4f  __attribute__((ext_vector_type(4)));

__device__ __forceinline__ float fdot2(unsigned int a, unsigned int b, float c) {
    return __builtin_amdgcn_fdot2(__builtin_bit_cast(h2_t, a),
                                  __builtin_bit_cast(h2_t, b), c, false);
}
__device__ __forceinline__ unsigned int packh2(float a, float b) {
    return __builtin_bit_cast(unsigned int, __builtin_amdgcn_cvt_pkrtz(a, b));
}

__global__ __launch_bounds__(512, 2) void rsa_kernel(const float* __restrict__ x,
                                                     float* __restrict__ out) {
    __shared__ uint4 sx[8 * NPOS];   // 61.4 KB: [grp][pos], 8 f16 ch per slot
    __shared__ float snf[NPOS];      // 1.9 KB : norms per halo position
    float* const trans = (float*)sx; // alias (sx dead after K-loop): 49*132*4=25.9KB

    const int tid = threadIdx.x;

    // ---- XCD-banded swizzle (R12-proven): xcd owns 4 contiguous tile-rows/batch
    const int id  = blockIdx.x;
    const int xcd = id & 7;
    const int seq = id >> 3;          // 0..63
    const int b   = seq >> 4;         // 0..3
    const int rem = seq & 15;
    const int by  = xcd * 4 + (rem >> 2);  // 0..31
    const int bx  = rem & 3;               // 0..3
    const int h0  = by * RH;
    const int w0  = bx * RW;
    const float* __restrict__ xb = x + (size_t)b * C * PLANE;

    // ---- staging: item = (g, hr, mi) -> 8 dwordx4 loads, pack, 4 b128 writes
#pragma unroll
    for (int j = 0; j < 2; ++j) {
        const int n = tid + j * 512;
        if (n < 800) {
            const int g   = n / 100;
            const int rm  = n - g * 100;
            const int hr  = rm / 10;
            const int mi  = rm - hr * 10;
            const int gh  = h0 + hr - 3;
            const int gw0 = w0 - 4 + 4 * mi;   // 16B-aligned (w0 % 32 == 0)
            const bool valid = (gh >= 0) && (gh < H) && (gw0 >= 0) && (gw0 + 3 < W);
            float4 va[8];
            if (valid) {
                const float* p = xb + (size_t)(8 * g) * PLANE + gh * W + gw0;
#pragma unroll
                for (int cc = 0; cc < 8; ++cc)
                    va[cc] = *(const float4*)(p + (size_t)cc * PLANE);
            } else {
#pragma unroll
                for (int cc = 0; cc < 8; ++cc)
                    va[cc] = make_float4(0.f, 0.f, 0.f, 0.f);
            }
#pragma unroll
            for (int e = 0; e < 4; ++e) {
                uint4 u;
                u.x = packh2(((const float*)&va[0])[e], ((const float*)&va[1])[e]);
                u.y = packh2(((const float*)&va[2])[e], ((const float*)&va[3])[e]);
                u.z = packh2(((const float*)&va[4])[e], ((const float*)&va[5])[e]);
                u.w = packh2(((const float*)&va[6])[e], ((const float*)&va[7])[e]);
                // slot col = 4*mi+e-1; col -1 wraps to prev row's pad col 39
                const int s = g * NPOS + hr * HWP + (4 * mi + e - 1);
                if (s >= 0) sx[s] = u;   // only (0,0,0,0) is s<0
            }
        }
    }
    __syncthreads();

    // ---- norms: read back each position's 8 packed slots
    if (tid < NPOS) {
        float sacc = 0.f;
#pragma unroll
        for (int g = 0; g < 8; ++g) {
            const uint4 u = sx[g * NPOS + tid];
            sacc = fdot2(u.x, u.x, sacc);
            sacc = fdot2(u.y, u.y, sacc);
            sacc = fdot2(u.z, u.z, sacc);
            sacc = fdot2(u.w, u.w, sacc);
        }
        snf[tid] = sqrtf(sacc);
    }
    __syncthreads();

    // ---- per-wave geometry: wave tc owns A-tile at cols tc*4
    const int lane = tid & 63;
    const int tc   = tid >> 6;        // 0..7 (wave index = A-tile col)
    const int quad = lane >> 4;       // ch-chunk for frags; px-row group for C
    const int l15  = lane & 15;
    const int sr   = l15 >> 2;        // spatial row within a 4x4 tile
    const int sc   = l15 & 3;         // spatial col within a 4x4 tile

    const int apos = (sr + 3) * HWP + (tc * 4 + sc + 3);

    v4f acc[9];
#pragma unroll
    for (int f = 0; f < 9; ++f) acc[f] = (v4f)0.f;

#pragma unroll
    for (int t = 0; t < 2; ++t) {
        const int grp = 4 * t + quad;
        const v8h a = __builtin_bit_cast(v8h, sx[grp * NPOS + apos]);
#pragma unroll
        for (int dr = 0; dr < 3; ++dr) {
#pragma unroll
            for (int dc = 0; dc < 3; ++dc) {
                const int bpos = (dr * 4 + sr) * HWP + (tc * 4 + dc * 4 + sc);
                const v8h bb = __builtin_bit_cast(v8h, sx[grp * NPOS + bpos]);
                acc[dr * 3 + dc] =
                    __builtin_amdgcn_mfma_f32_16x16x32_f16(a, bb, acc[dr * 3 + dc], 0, 0, 0);
            }
        }
    }

    // ---- epilogue: C-layout col n = l15 (B pos), row m = quad*4 + reg (A px)
    float ncv[4];
#pragma unroll
    for (int r = 0; r < 4; ++r)
        ncv[r] = snf[(quad + 3) * HWP + (tc * 4 + r + 3)];
    float nnv[9];
#pragma unroll
    for (int f = 0; f < 9; ++f) {
        const int dr = f / 3, dc = f % 3;
        nnv[f] = snf[(dr * 4 + sr) * HWP + (tc * 4 + dc * 4 + sc)];
    }

    float mx[4] = {-1e30f, -1e30f, -1e30f, -1e30f};
#pragma unroll
    for (int f = 0; f < 9; ++f) {
        const int dr = f / 3, dc = f % 3;
        const int d0 = dr * 4 + sr - quad;       // window-row idx if in [0,6]
#pragma unroll
        for (int r = 0; r < 4; ++r) {
            const int de = dc * 4 + sc - r;      // window-col idx if in [0,6]
            const bool val = ((unsigned)d0 <= 6u) && ((unsigned)de <= 6u);
            const float sv = __fdividef(acc[f][r], ncv[r] * nnv[f] + EPS);
            acc[f][r] = sv;
            if (val) mx[r] = fmaxf(mx[r], sv);
        }
    }
#pragma unroll
    for (int wd = 1; wd < 16; wd <<= 1)
#pragma unroll
        for (int r = 0; r < 4; ++r)
            mx[r] = fmaxf(mx[r], __shfl_xor(mx[r], wd, 64));

    float sm[4] = {0.f, 0.f, 0.f, 0.f};
#pragma unroll
    for (int f = 0; f < 9; ++f) {
        const int dr = f / 3, dc = f % 3;
        const int d0 = dr * 4 + sr - quad;
#pragma unroll
        for (int r = 0; r < 4; ++r) {
            const int de = dc * 4 + sc - r;
            const bool val = ((unsigned)d0 <= 6u) && ((unsigned)de <= 6u);
            const float e = val ? __expf(acc[f][r] - mx[r]) : 0.f;
            acc[f][r] = e;
            sm[r] += e;
        }
    }
#pragma unroll
    for (int wd = 1; wd < 16; wd <<= 1)
#pragma unroll
        for (int r = 0; r < 4; ++r)
            sm[r] += __shfl_xor(sm[r], wd, 64);

    // ---- transpose through LDS (aliases sx) for full-line global stores
    __syncthreads();   // all sx (K-loop) reads complete before trans writes
#pragma unroll
    for (int r = 0; r < 4; ++r) {
        const float inv = __fdividef(1.f, sm[r]);
        const int px = quad * 32 + tc * 4 + r;   // local px index (row*32+col)
#pragma unroll
        for (int f = 0; f < 9; ++f) {
            const int dr = f / 3, dc = f % 3;
            const int d0 = dr * 4 + sr - quad;
            const int de = dc * 4 + sc - r;
            if (((unsigned)d0 <= 6u) && ((unsigned)de <= 6u)) {
                const int k = d0 * 7 + de;
                trans[k * TSTR + px] = acc[f][r] * inv;
            }
        }
    }
    __syncthreads();

    const size_t obase = ((size_t)b * KK) << 14;
#pragma unroll
    for (int j = 0; j < 13; ++j) {
        const int n = tid + j * 512;             // n = k*128 + px, n < 6272
        if (n < KK * 128) {
            const int k  = n >> 7;
            const int px = n & 127;
            const int gh = h0 + (px >> 5);
            const int gw = w0 + (px & 31);
            out[obase + ((size_t)k << 14) + (gh << 7) + gw] = trans[k * TSTR + px];
        }
    }
}

extern "C" void kernel_launch(void* const* d_in, const int* in_sizes, int n_in,
                              void* d_out, int out_size, void* d_ws, size_t ws_size,
                              hipStream_t stream) {
    const float* x = (const float*)d_in[0];
    float* out = (float*)d_out;

    dim3 block(512, 1, 1);
    dim3 grid(512, 1, 1);  // 2 blocks/CU, 16 waves/CU; XCD-banded decode inside
    rsa_kernel<<<grid, block, 0, stream>>>(x, out);
}